// Round 1
// baseline (12484.570 us; speedup 1.0000x reference)
//
#include <hip/hip_runtime.h>
#include <hip/hip_bf16.h>
#include <math.h>

#define B_ 32
#define S_ 511
#define T_ 512
#define D_ 512
#define H_ 8
#define HD_ 64
#define L_ 4
#define P_ 501
#define PD_ 32
#define FD_ 448
#define DFF_ 2048

// ---------------- embedding + positional encoding ----------------
__global__ __launch_bounds__(256) void embed_kernel(
    const float* __restrict__ runs, const float* __restrict__ wickets,
    const float* __restrict__ overs, const int* __restrict__ batters,
    const int* __restrict__ bowlers, const float* __restrict__ pemb,
    const float* __restrict__ Wf, const float* __restrict__ bfv,
    const float* __restrict__ qtok, float* __restrict__ x)
{
  size_t idx = (size_t)blockIdx.x * 256 + threadIdx.x;
  const size_t total = (size_t)B_ * T_ * D_;
  if (idx >= total) return;
  int d = (int)(idx % D_);
  int t = (int)((idx / D_) % T_);
  int b = (int)(idx / ((size_t)D_ * T_));
  float val;
  if (t < S_) {
    size_t st = (size_t)b * S_ + t;
    if (d < FD_) {
      val = runs[st] * Wf[d] + wickets[st] * Wf[FD_ + d] + overs[st] * Wf[2 * FD_ + d] + bfv[d];
    } else if (d < FD_ + PD_) {
      val = pemb[(size_t)batters[st] * PD_ + (d - FD_)];
    } else {
      val = pemb[(size_t)bowlers[st] * PD_ + (d - FD_ - PD_)];
    }
  } else {
    val = qtok[d];
  }
  // sinusoidal PE: i = d/2, div = exp(-(2i)*ln(10000)/D)
  float div = expf((float)(2 * (d >> 1)) * (-9.210340371976184f / (float)D_));
  float ang = (float)t * div;
  val += (d & 1) ? cosf(ang) : sinf(ang);
  x[idx] = val;
}

// ---------------- generic fp32 GEMM: C = A[M,K] @ W[K,N] + bias, act ----------------
// 64x64 tile, 256 threads, 4x4 accumulators per thread, KT=16
__global__ __launch_bounds__(256) void gemm_kernel(
    const float* __restrict__ A, const float* __restrict__ W,
    const float* __restrict__ bias, float* __restrict__ C,
    int M, int N, int K, int act)
{
  __shared__ float As[16][64];
  __shared__ float Wsh[16][64];
  int tid = threadIdx.x;
  int tx = tid & 15, ty = tid >> 4;
  int row0 = blockIdx.y * 64, col0 = blockIdx.x * 64;
  float acc[4][4] = {{0.f, 0.f, 0.f, 0.f}, {0.f, 0.f, 0.f, 0.f},
                     {0.f, 0.f, 0.f, 0.f}, {0.f, 0.f, 0.f, 0.f}};
  int ar = tid >> 2, ac4 = (tid & 3) << 2;   // A: 64 rows x 16 k, float4 per thread
  int wk = tid >> 4, wn4 = (tid & 15) << 2;  // W: 16 k x 64 n, float4 per thread
  for (int k0 = 0; k0 < K; k0 += 16) {
    float4 a4 = *(const float4*)(A + (size_t)(row0 + ar) * K + k0 + ac4);
    float4 w4 = *(const float4*)(W + (size_t)(k0 + wk) * N + col0 + wn4);
    As[ac4 + 0][ar] = a4.x; As[ac4 + 1][ar] = a4.y;
    As[ac4 + 2][ar] = a4.z; As[ac4 + 3][ar] = a4.w;
    Wsh[wk][wn4 + 0] = w4.x; Wsh[wk][wn4 + 1] = w4.y;
    Wsh[wk][wn4 + 2] = w4.z; Wsh[wk][wn4 + 3] = w4.w;
    __syncthreads();
#pragma unroll
    for (int kk = 0; kk < 16; ++kk) {
      float4 av = *(const float4*)&As[kk][ty << 2];
      float4 wv = *(const float4*)&Wsh[kk][tx << 2];
      float aa[4] = {av.x, av.y, av.z, av.w};
      float ww[4] = {wv.x, wv.y, wv.z, wv.w};
#pragma unroll
      for (int i = 0; i < 4; ++i)
#pragma unroll
        for (int j = 0; j < 4; ++j)
          acc[i][j] = fmaf(aa[i], ww[j], acc[i][j]);
    }
    __syncthreads();
  }
#pragma unroll
  for (int i = 0; i < 4; ++i) {
    int row = row0 + (ty << 2) + i;
#pragma unroll
    for (int j = 0; j < 4; ++j) {
      int col = col0 + (tx << 2) + j;
      float vv = acc[i][j] + bias[col];
      if (act == 1) vv = 0.5f * vv * (1.0f + erff(vv * 0.70710678118654752f));
      C[(size_t)row * N + col] = vv;
    }
  }
}

// ---------------- attention: one block per (q-row, head, batch) ----------------
__global__ __launch_bounds__(256) void attn_kernel(
    const float* __restrict__ q, const float* __restrict__ k,
    const float* __restrict__ v, float* __restrict__ o,
    const int* __restrict__ batters, const int* __restrict__ bowlers,
    const float* __restrict__ rec_sp, const float* __restrict__ bow_sp,
    const float* __restrict__ bat_sp, int l)
{
  int t = blockIdx.x, h = blockIdx.y, b = blockIdx.z;
  int tid = threadIdx.x;
  __shared__ float qs[HD_];
  __shared__ float sc[T_];
  __shared__ float part[4][HD_];
  __shared__ float red[4];

  const float* qp = q + ((size_t)b * T_ + t) * D_ + h * HD_;
  if (tid < HD_) qs[tid] = qp[tid];
  __syncthreads();

  const float scale = 0.125f;  // 1/sqrt(64)
  int kk0 = tid, kk1 = tid + 256;
  float s0 = -INFINITY, s1 = -INFINITY;

  // head-specialized bias
  int mode = 0; float hs = 0.f;
  if (h == 0) { mode = 1; hs = rec_sp[l]; }
  else if (h == 1) { mode = 2; hs = bow_sp[l]; }
  else if (h == 2) { mode = 3; hs = bat_sp[l]; }
  const int* actors = (mode == 2) ? bowlers : batters;
  int my_actor = 0;
  if ((mode == 2 || mode == 3) && t < S_) my_actor = actors[(size_t)b * S_ + t];

#pragma unroll
  for (int pass = 0; pass < 2; ++pass) {
    int kk = (pass == 0) ? kk0 : kk1;
    if (kk <= t) {
      const float* kp = k + ((size_t)b * T_ + kk) * D_ + h * HD_;
      float dacc = 0.f;
#pragma unroll
      for (int i = 0; i < HD_; ++i) dacc += qs[i] * kp[i];
      float s = dacc * scale;
      if (mode == 1) {
        s += hs * (float)kk * (1.0f / (float)T_);
      } else if (mode == 2 || mode == 3) {
        float eq = (t == S_ || kk == S_) ? 1.0f
                   : ((my_actor == actors[(size_t)b * S_ + kk]) ? 1.0f : 0.0f);
        s += hs * eq;
      }
      if (pass == 0) s0 = s; else s1 = s;
    }
  }

  // block max
  float m = fmaxf(s0, s1);
#pragma unroll
  for (int off = 32; off > 0; off >>= 1) m = fmaxf(m, __shfl_down(m, off));
  if ((tid & 63) == 0) red[tid >> 6] = m;
  __syncthreads();
  m = fmaxf(fmaxf(red[0], red[1]), fmaxf(red[2], red[3]));
  __syncthreads();

  float e0 = (kk0 <= t) ? expf(s0 - m) : 0.0f;
  float e1 = (kk1 <= t) ? expf(s1 - m) : 0.0f;
  sc[kk0] = e0; sc[kk1] = e1;
  float sm = e0 + e1;
#pragma unroll
  for (int off = 32; off > 0; off >>= 1) sm += __shfl_down(sm, off);
  if ((tid & 63) == 0) red[tid >> 6] = sm;
  __syncthreads();  // also makes sc[] visible to all
  float inv = 1.0f / (red[0] + red[1] + red[2] + red[3]);

  // PV: tid = d + 64*g ; group g handles keys g, g+4, ...
  int d = tid & 63, g = tid >> 6;
  float acc = 0.f;
  for (int kk = g; kk <= t; kk += 4) {
    acc += sc[kk] * v[((size_t)b * T_ + kk) * D_ + h * HD_ + d];
  }
  part[g][d] = acc;
  __syncthreads();
  if (g == 0) {
    float tot = (part[0][d] + part[1][d] + part[2][d] + part[3][d]) * inv;
    o[((size_t)b * T_ + t) * D_ + h * HD_ + d] = tot;
  }
}

// ---------------- residual add + LayerNorm (one block per row) ----------------
__global__ __launch_bounds__(256) void add_ln_kernel(
    float* __restrict__ x, const float* __restrict__ y,
    const float* __restrict__ g, const float* __restrict__ be)
{
  int row = blockIdx.x;
  int tid = threadIdx.x;
  size_t base = (size_t)row * D_;
  float v0 = x[base + tid] + y[base + tid];
  float v1 = x[base + tid + 256] + y[base + tid + 256];
  float s = v0 + v1;
  float s2 = v0 * v0 + v1 * v1;
  __shared__ float redA[4], redB[4];
#pragma unroll
  for (int off = 32; off > 0; off >>= 1) {
    s  += __shfl_down(s, off);
    s2 += __shfl_down(s2, off);
  }
  if ((tid & 63) == 0) { redA[tid >> 6] = s; redB[tid >> 6] = s2; }
  __syncthreads();
  float st  = redA[0] + redA[1] + redA[2] + redA[3];
  float s2t = redB[0] + redB[1] + redB[2] + redB[3];
  float mu = st * (1.0f / (float)D_);
  float var = s2t * (1.0f / (float)D_) - mu * mu;
  float r = rsqrtf(var + 1e-5f);
  x[base + tid]       = (v0 - mu) * r * g[tid] + be[tid];
  x[base + tid + 256] = (v1 - mu) * r * g[tid + 256] + be[tid + 256];
}

// ---------------- final: out[b,:] = x[b,T-1,:] @ Wout + bout ----------------
__global__ __launch_bounds__(256) void final_kernel(
    const float* __restrict__ x, const float* __restrict__ Wout,
    const float* __restrict__ bout, float* __restrict__ out)
{
  __shared__ float xs[D_];
  int b = blockIdx.x;
  int n = blockIdx.y * 256 + threadIdx.x;
  const float* xr = x + ((size_t)b * T_ + (T_ - 1)) * D_;
  xs[threadIdx.x] = xr[threadIdx.x];
  xs[threadIdx.x + 256] = xr[threadIdx.x + 256];
  __syncthreads();
  float acc = bout[n];
  for (int kk = 0; kk < D_; ++kk)
    acc = fmaf(xs[kk], Wout[(size_t)kk * D_ + n], acc);
  out[(size_t)b * D_ + n] = acc;
}

extern "C" void kernel_launch(void* const* d_in, const int* in_sizes, int n_in,
                              void* d_out, int out_size, void* d_ws, size_t ws_size,
                              hipStream_t stream)
{
  const float* runs    = (const float*)d_in[0];
  const float* wickets = (const float*)d_in[1];
  const float* overs   = (const float*)d_in[2];
  const int*   batters = (const int*)d_in[3];
  const int*   bowlers = (const int*)d_in[4];
  const float* pemb    = (const float*)d_in[5];
  const float* Wf      = (const float*)d_in[6];
  const float* bfv     = (const float*)d_in[7];
  const float* qtok    = (const float*)d_in[8];
  const float* Wq      = (const float*)d_in[9];
  const float* bq      = (const float*)d_in[10];
  const float* Wk      = (const float*)d_in[11];
  const float* bk      = (const float*)d_in[12];
  const float* Wv      = (const float*)d_in[13];
  const float* bv      = (const float*)d_in[14];
  const float* Wo      = (const float*)d_in[15];
  const float* bo      = (const float*)d_in[16];
  const float* rec_s   = (const float*)d_in[17];
  const float* bow_s   = (const float*)d_in[18];
  const float* bat_s   = (const float*)d_in[19];
  const float* W1      = (const float*)d_in[20];
  const float* b1      = (const float*)d_in[21];
  const float* W2      = (const float*)d_in[22];
  const float* b2      = (const float*)d_in[23];
  const float* g1      = (const float*)d_in[24];
  const float* be1     = (const float*)d_in[25];
  const float* g2      = (const float*)d_in[26];
  const float* be2     = (const float*)d_in[27];
  const float* Wout    = (const float*)d_in[28];
  const float* bout    = (const float*)d_in[29];

  float* ws = (float*)d_ws;
  const size_t n1 = (size_t)B_ * T_ * D_;  // 8388608 floats
  float* x  = ws;
  float* qb = ws + n1;
  float* kb = ws + 2 * n1;
  float* vb = ws + 3 * n1;
  float* ob = ws + 4 * n1;
  float* yb = ws + 5 * n1;
  float* hb = qb;  // FFN hidden reuses q/k/v/o region: 4*n1 == B*T*DFF

  const int M = B_ * T_;
  dim3 blk(256);

  {
    size_t total = (size_t)B_ * T_ * D_;
    int nb = (int)((total + 255) / 256);
    embed_kernel<<<nb, blk, 0, stream>>>(runs, wickets, overs, batters, bowlers,
                                         pemb, Wf, bfv, qtok, x);
  }

  for (int l = 0; l < L_; ++l) {
    const float* Wq_l = Wq + (size_t)l * D_ * D_;
    const float* Wk_l = Wk + (size_t)l * D_ * D_;
    const float* Wv_l = Wv + (size_t)l * D_ * D_;
    const float* Wo_l = Wo + (size_t)l * D_ * D_;
    const float* W1_l = W1 + (size_t)l * D_ * DFF_;
    const float* W2_l = W2 + (size_t)l * DFF_ * D_;

    gemm_kernel<<<dim3(D_ / 64, M / 64), blk, 0, stream>>>(x, Wq_l, bq + l * D_, qb, M, D_, D_, 0);
    gemm_kernel<<<dim3(D_ / 64, M / 64), blk, 0, stream>>>(x, Wk_l, bk + l * D_, kb, M, D_, D_, 0);
    gemm_kernel<<<dim3(D_ / 64, M / 64), blk, 0, stream>>>(x, Wv_l, bv + l * D_, vb, M, D_, D_, 0);

    attn_kernel<<<dim3(T_, H_, B_), blk, 0, stream>>>(qb, kb, vb, ob, batters, bowlers,
                                                      rec_s, bow_s, bat_s, l);

    gemm_kernel<<<dim3(D_ / 64, M / 64), blk, 0, stream>>>(ob, Wo_l, bo + l * D_, yb, M, D_, D_, 0);
    add_ln_kernel<<<M, blk, 0, stream>>>(x, yb, g1 + l * D_, be1 + l * D_);

    gemm_kernel<<<dim3(DFF_ / 64, M / 64), blk, 0, stream>>>(x, W1_l, b1 + l * DFF_, hb, M, DFF_, D_, 1);
    gemm_kernel<<<dim3(D_ / 64, M / 64), blk, 0, stream>>>(hb, W2_l, b2 + l * D_, yb, M, D_, DFF_, 0);
    add_ln_kernel<<<M, blk, 0, stream>>>(x, yb, g2 + l * D_, be2 + l * D_);
  }

  final_kernel<<<dim3(B_, D_ / 256), blk, 0, stream>>>(x, Wout, bout, (float*)d_out);
}

// Round 2
// 7737.132 us; speedup vs baseline: 1.6136x; 1.6136x over previous
//
#include <hip/hip_runtime.h>
#include <hip/hip_bf16.h>
#include <math.h>

#define B_ 32
#define S_ 511
#define T_ 512
#define D_ 512
#define H_ 8
#define HD_ 64
#define L_ 4
#define P_ 501
#define PD_ 32
#define FD_ 448
#define DFF_ 2048

// ---------------- embedding + positional encoding ----------------
__global__ __launch_bounds__(256) void embed_kernel(
    const float* __restrict__ runs, const float* __restrict__ wickets,
    const float* __restrict__ overs, const int* __restrict__ batters,
    const int* __restrict__ bowlers, const float* __restrict__ pemb,
    const float* __restrict__ Wf, const float* __restrict__ bfv,
    const float* __restrict__ qtok, float* __restrict__ x)
{
  size_t idx = (size_t)blockIdx.x * 256 + threadIdx.x;
  const size_t total = (size_t)B_ * T_ * D_;
  if (idx >= total) return;
  int d = (int)(idx % D_);
  int t = (int)((idx / D_) % T_);
  int b = (int)(idx / ((size_t)D_ * T_));
  float val;
  if (t < S_) {
    size_t st = (size_t)b * S_ + t;
    if (d < FD_) {
      val = runs[st] * Wf[d] + wickets[st] * Wf[FD_ + d] + overs[st] * Wf[2 * FD_ + d] + bfv[d];
    } else if (d < FD_ + PD_) {
      val = pemb[(size_t)batters[st] * PD_ + (d - FD_)];
    } else {
      val = pemb[(size_t)bowlers[st] * PD_ + (d - FD_ - PD_)];
    }
  } else {
    val = qtok[d];
  }
  float div = expf((float)(2 * (d >> 1)) * (-9.210340371976184f / (float)D_));
  float ang = (float)t * div;
  val += (d & 1) ? cosf(ang) : sinf(ang);
  x[idx] = val;
}

// ---------------- generic fp32 GEMM: C = A[M,K] @ W[K,N] + bias, act ----------------
__global__ __launch_bounds__(256) void gemm_kernel(
    const float* __restrict__ A, const float* __restrict__ W,
    const float* __restrict__ bias, float* __restrict__ C,
    int M, int N, int K, int act)
{
  __shared__ float As[16][64];
  __shared__ float Wsh[16][64];
  int tid = threadIdx.x;
  int tx = tid & 15, ty = tid >> 4;
  int row0 = blockIdx.y * 64, col0 = blockIdx.x * 64;
  float acc[4][4] = {{0.f, 0.f, 0.f, 0.f}, {0.f, 0.f, 0.f, 0.f},
                     {0.f, 0.f, 0.f, 0.f}, {0.f, 0.f, 0.f, 0.f}};
  int ar = tid >> 2, ac4 = (tid & 3) << 2;
  int wk = tid >> 4, wn4 = (tid & 15) << 2;
  for (int k0 = 0; k0 < K; k0 += 16) {
    float4 a4 = *(const float4*)(A + (size_t)(row0 + ar) * K + k0 + ac4);
    float4 w4 = *(const float4*)(W + (size_t)(k0 + wk) * N + col0 + wn4);
    As[ac4 + 0][ar] = a4.x; As[ac4 + 1][ar] = a4.y;
    As[ac4 + 2][ar] = a4.z; As[ac4 + 3][ar] = a4.w;
    Wsh[wk][wn4 + 0] = w4.x; Wsh[wk][wn4 + 1] = w4.y;
    Wsh[wk][wn4 + 2] = w4.z; Wsh[wk][wn4 + 3] = w4.w;
    __syncthreads();
#pragma unroll
    for (int kk = 0; kk < 16; ++kk) {
      float4 av = *(const float4*)&As[kk][ty << 2];
      float4 wv = *(const float4*)&Wsh[kk][tx << 2];
      float aa[4] = {av.x, av.y, av.z, av.w};
      float ww[4] = {wv.x, wv.y, wv.z, wv.w};
#pragma unroll
      for (int i = 0; i < 4; ++i)
#pragma unroll
        for (int j = 0; j < 4; ++j)
          acc[i][j] = fmaf(aa[i], ww[j], acc[i][j]);
    }
    __syncthreads();
  }
#pragma unroll
  for (int i = 0; i < 4; ++i) {
    int row = row0 + (ty << 2) + i;
#pragma unroll
    for (int j = 0; j < 4; ++j) {
      int col = col0 + (tx << 2) + j;
      float vv = acc[i][j] + bias[col];
      if (act == 1) vv = 0.5f * vv * (1.0f + erff(vv * 0.70710678118654752f));
      C[(size_t)row * N + col] = vv;
    }
  }
}

// ---------------- tiled flash attention (fp32) ----------------
// block = 256 threads, one block per (b, h, 64-query tile)
// LDS: Qs [d][q] 65-stride, KVs [d][k] (K for QK^T, then V for PV), Ps [q][k]
__global__ __launch_bounds__(256) void flash_attn_kernel(
    const float* __restrict__ q, const float* __restrict__ k,
    const float* __restrict__ v, float* __restrict__ o,
    const int* __restrict__ batters, const int* __restrict__ bowlers,
    const float* __restrict__ rec_sp, const float* __restrict__ bow_sp,
    const float* __restrict__ bat_sp, int l)
{
  __shared__ float Qs[64][65];
  __shared__ float KVs[64][65];
  __shared__ float Ps[64][65];
  __shared__ float mrow[64], lrow[64], crow[64];
  __shared__ int aq_s[64], ak_s[64];

  const int qt = blockIdx.x, h = blockIdx.y, b = blockIdx.z;
  const int tid = threadIdx.x;
  const int tx = tid & 15, ty = tid >> 4;
  // loader mapping: 4 consecutive lanes cover one contiguous 256B row
  const int lr = tid >> 2, ldc = tid & 3;

  int mode = 0; float hs = 0.f;
  if (h == 0) { mode = 1; hs = rec_sp[l]; }
  else if (h == 1) { mode = 2; hs = bow_sp[l]; }
  else if (h == 2) { mode = 3; hs = bat_sp[l]; }
  const int* actors = (mode == 2) ? bowlers : batters;

  const int q0 = qt * 64;

  // load Q tile transposed into Qs[d][q]
  {
    const float* qp = q + ((size_t)b * T_ + q0 + lr) * D_ + h * HD_ + ldc * 16;
#pragma unroll
    for (int j = 0; j < 4; ++j) {
      float4 t4 = *(const float4*)(qp + 4 * j);
      int d0 = ldc * 16 + 4 * j;
      Qs[d0 + 0][lr] = t4.x; Qs[d0 + 1][lr] = t4.y;
      Qs[d0 + 2][lr] = t4.z; Qs[d0 + 3][lr] = t4.w;
    }
  }
  if (tid < 64) {
    int qg = q0 + tid;
    aq_s[tid] = (mode >= 2 && qg < S_) ? actors[(size_t)b * S_ + qg] : -1;
    mrow[tid] = -INFINITY;
    lrow[tid] = 0.f;
  }

  float o_acc[4][4] = {{0.f,0.f,0.f,0.f},{0.f,0.f,0.f,0.f},
                       {0.f,0.f,0.f,0.f},{0.f,0.f,0.f,0.f}};

  for (int kt = 0; kt <= qt; ++kt) {
    const int k0 = kt * 64;
    __syncthreads();  // protect KVs/Ps overwrite vs previous PV phase
    // load K tile transposed into KVs[d][k]
    {
      const float* kp = k + ((size_t)b * T_ + k0 + lr) * D_ + h * HD_ + ldc * 16;
#pragma unroll
      for (int j = 0; j < 4; ++j) {
        float4 t4 = *(const float4*)(kp + 4 * j);
        int d0 = ldc * 16 + 4 * j;
        KVs[d0 + 0][lr] = t4.x; KVs[d0 + 1][lr] = t4.y;
        KVs[d0 + 2][lr] = t4.z; KVs[d0 + 3][lr] = t4.w;
      }
    }
    if (tid < 64) {
      int kg = k0 + tid;
      ak_s[tid] = (mode >= 2 && kg < S_) ? actors[(size_t)b * S_ + kg] : -1;
    }
    __syncthreads();

    // ---- QK^T: thread owns S[4 q][4 k], q = 4ty+i, k = 4tx+j ----
    float acc[4][4] = {{0.f,0.f,0.f,0.f},{0.f,0.f,0.f,0.f},
                       {0.f,0.f,0.f,0.f},{0.f,0.f,0.f,0.f}};
#pragma unroll 16
    for (int d = 0; d < 64; ++d) {
      const float4 qv = *(const float4*)&Qs[d][ty * 4];
      const float4 kv = *(const float4*)&KVs[d][tx * 4];
      acc[0][0] = fmaf(qv.x, kv.x, acc[0][0]);
      acc[0][1] = fmaf(qv.x, kv.y, acc[0][1]);
      acc[0][2] = fmaf(qv.x, kv.z, acc[0][2]);
      acc[0][3] = fmaf(qv.x, kv.w, acc[0][3]);
      acc[1][0] = fmaf(qv.y, kv.x, acc[1][0]);
      acc[1][1] = fmaf(qv.y, kv.y, acc[1][1]);
      acc[1][2] = fmaf(qv.y, kv.z, acc[1][2]);
      acc[1][3] = fmaf(qv.y, kv.w, acc[1][3]);
      acc[2][0] = fmaf(qv.z, kv.x, acc[2][0]);
      acc[2][1] = fmaf(qv.z, kv.y, acc[2][1]);
      acc[2][2] = fmaf(qv.z, kv.z, acc[2][2]);
      acc[2][3] = fmaf(qv.z, kv.w, acc[2][3]);
      acc[3][0] = fmaf(qv.w, kv.x, acc[3][0]);
      acc[3][1] = fmaf(qv.w, kv.y, acc[3][1]);
      acc[3][2] = fmaf(qv.w, kv.z, acc[3][2]);
      acc[3][3] = fmaf(qv.w, kv.w, acc[3][3]);
    }
    // scale + head bias + causal mask -> raw scores to Ps[q][k]
    {
      const int qg0 = q0 + ty * 4, kg0 = k0 + tx * 4;
#pragma unroll
      for (int i = 0; i < 4; ++i) {
        float4 sv;
        float* sp = (float*)&sv;
        const int qg = qg0 + i;
        const int aq = aq_s[ty * 4 + i];
#pragma unroll
        for (int j = 0; j < 4; ++j) {
          const int kg = kg0 + j;
          float s = acc[i][j] * 0.125f;
          if (mode == 1) {
            s = fmaf(hs, (float)kg * (1.0f / (float)T_), s);
          } else if (mode >= 2) {
            float eq = (qg == S_ || kg == S_) ? 1.0f
                       : ((aq == ak_s[tx * 4 + j]) ? 1.0f : 0.0f);
            s = fmaf(hs, eq, s);
          }
          if (kg > qg) s = -INFINITY;
          sp[j] = s;
        }
        *(float4*)&Ps[ty * 4 + i][tx * 4] = sv;
      }
    }
    __syncthreads();

    // ---- load V tile transposed into KVs (K no longer needed) ----
    {
      const float* vp = v + ((size_t)b * T_ + k0 + lr) * D_ + h * HD_ + ldc * 16;
#pragma unroll
      for (int j = 0; j < 4; ++j) {
        float4 t4 = *(const float4*)(vp + 4 * j);
        int d0 = ldc * 16 + 4 * j;
        KVs[d0 + 0][lr] = t4.x; KVs[d0 + 1][lr] = t4.y;
        KVs[d0 + 2][lr] = t4.z; KVs[d0 + 3][lr] = t4.w;
      }
    }
    // ---- online softmax: 4 threads per q-row ----
    {
      const int qq = tid >> 2, p = tid & 3;
      float4 va[4];
#pragma unroll
      for (int u = 0; u < 4; ++u) va[u] = *(const float4*)&Ps[qq][p * 16 + 4 * u];
      float m = -INFINITY;
#pragma unroll
      for (int u = 0; u < 4; ++u) {
        m = fmaxf(m, fmaxf(fmaxf(va[u].x, va[u].y), fmaxf(va[u].z, va[u].w)));
      }
      m = fmaxf(m, __shfl_xor(m, 1));
      m = fmaxf(m, __shfl_xor(m, 2));
      const float m_old = mrow[qq];
      const float m_new = fmaxf(m_old, m);
      float sum = 0.f;
#pragma unroll
      for (int u = 0; u < 4; ++u) {
        va[u].x = expf(va[u].x - m_new);
        va[u].y = expf(va[u].y - m_new);
        va[u].z = expf(va[u].z - m_new);
        va[u].w = expf(va[u].w - m_new);
        sum += va[u].x + va[u].y + va[u].z + va[u].w;
        *(float4*)&Ps[qq][p * 16 + 4 * u] = va[u];
      }
      sum += __shfl_xor(sum, 1);
      sum += __shfl_xor(sum, 2);
      if (p == 0) {
        const float c = expf(m_old - m_new);
        crow[qq] = c;
        lrow[qq] = lrow[qq] * c + sum;
        mrow[qq] = m_new;
      }
    }
    __syncthreads();

    // ---- PV: o_acc[i][j] = o_acc*c + sum_k P[q][k] * V[k][d] ----
    {
#pragma unroll
      for (int i = 0; i < 4; ++i) {
        const float c = crow[ty * 4 + i];
#pragma unroll
        for (int j = 0; j < 4; ++j) o_acc[i][j] *= c;
      }
#pragma unroll 4
      for (int k4 = 0; k4 < 64; k4 += 4) {
        float4 pv[4], vv[4];
#pragma unroll
        for (int i = 0; i < 4; ++i) pv[i] = *(const float4*)&Ps[ty * 4 + i][k4];
#pragma unroll
        for (int j = 0; j < 4; ++j) vv[j] = *(const float4*)&KVs[tx * 4 + j][k4];
#pragma unroll
        for (int i = 0; i < 4; ++i)
#pragma unroll
          for (int j = 0; j < 4; ++j)
            o_acc[i][j] = fmaf(pv[i].x, vv[j].x,
                          fmaf(pv[i].y, vv[j].y,
                          fmaf(pv[i].z, vv[j].z,
                          fmaf(pv[i].w, vv[j].w, o_acc[i][j]))));
      }
    }
  }

  // epilogue: normalize by running sum, write out
#pragma unroll
  for (int i = 0; i < 4; ++i) {
    const float inv = 1.0f / lrow[ty * 4 + i];
    float4 ov = make_float4(o_acc[i][0] * inv, o_acc[i][1] * inv,
                            o_acc[i][2] * inv, o_acc[i][3] * inv);
    *(float4*)&o[((size_t)b * T_ + q0 + ty * 4 + i) * D_ + h * HD_ + tx * 4] = ov;
  }
}

// ---------------- residual add + LayerNorm (one block per row) ----------------
__global__ __launch_bounds__(256) void add_ln_kernel(
    float* __restrict__ x, const float* __restrict__ y,
    const float* __restrict__ g, const float* __restrict__ be)
{
  int row = blockIdx.x;
  int tid = threadIdx.x;
  size_t base = (size_t)row * D_;
  float v0 = x[base + tid] + y[base + tid];
  float v1 = x[base + tid + 256] + y[base + tid + 256];
  float s = v0 + v1;
  float s2 = v0 * v0 + v1 * v1;
  __shared__ float redA[4], redB[4];
#pragma unroll
  for (int off = 32; off > 0; off >>= 1) {
    s  += __shfl_down(s, off);
    s2 += __shfl_down(s2, off);
  }
  if ((tid & 63) == 0) { redA[tid >> 6] = s; redB[tid >> 6] = s2; }
  __syncthreads();
  float st  = redA[0] + redA[1] + redA[2] + redA[3];
  float s2t = redB[0] + redB[1] + redB[2] + redB[3];
  float mu = st * (1.0f / (float)D_);
  float var = s2t * (1.0f / (float)D_) - mu * mu;
  float r = rsqrtf(var + 1e-5f);
  x[base + tid]       = (v0 - mu) * r * g[tid] + be[tid];
  x[base + tid + 256] = (v1 - mu) * r * g[tid + 256] + be[tid + 256];
}

// ---------------- final: out[b,:] = x[b,T-1,:] @ Wout + bout ----------------
__global__ __launch_bounds__(256) void final_kernel(
    const float* __restrict__ x, const float* __restrict__ Wout,
    const float* __restrict__ bout, float* __restrict__ out)
{
  __shared__ float xs[D_];
  int b = blockIdx.x;
  int n = blockIdx.y * 256 + threadIdx.x;
  const float* xr = x + ((size_t)b * T_ + (T_ - 1)) * D_;
  xs[threadIdx.x] = xr[threadIdx.x];
  xs[threadIdx.x + 256] = xr[threadIdx.x + 256];
  __syncthreads();
  float acc = bout[n];
  for (int kk = 0; kk < D_; ++kk)
    acc = fmaf(xs[kk], Wout[(size_t)kk * D_ + n], acc);
  out[(size_t)b * D_ + n] = acc;
}

extern "C" void kernel_launch(void* const* d_in, const int* in_sizes, int n_in,
                              void* d_out, int out_size, void* d_ws, size_t ws_size,
                              hipStream_t stream)
{
  const float* runs    = (const float*)d_in[0];
  const float* wickets = (const float*)d_in[1];
  const float* overs   = (const float*)d_in[2];
  const int*   batters = (const int*)d_in[3];
  const int*   bowlers = (const int*)d_in[4];
  const float* pemb    = (const float*)d_in[5];
  const float* Wf      = (const float*)d_in[6];
  const float* bfv     = (const float*)d_in[7];
  const float* qtok    = (const float*)d_in[8];
  const float* Wq      = (const float*)d_in[9];
  const float* bq      = (const float*)d_in[10];
  const float* Wk      = (const float*)d_in[11];
  const float* bk      = (const float*)d_in[12];
  const float* Wv      = (const float*)d_in[13];
  const float* bv      = (const float*)d_in[14];
  const float* Wo      = (const float*)d_in[15];
  const float* bo      = (const float*)d_in[16];
  const float* rec_s   = (const float*)d_in[17];
  const float* bow_s   = (const float*)d_in[18];
  const float* bat_s   = (const float*)d_in[19];
  const float* W1      = (const float*)d_in[20];
  const float* b1      = (const float*)d_in[21];
  const float* W2      = (const float*)d_in[22];
  const float* b2      = (const float*)d_in[23];
  const float* g1      = (const float*)d_in[24];
  const float* be1     = (const float*)d_in[25];
  const float* g2      = (const float*)d_in[26];
  const float* be2     = (const float*)d_in[27];
  const float* Wout    = (const float*)d_in[28];
  const float* bout    = (const float*)d_in[29];

  float* ws = (float*)d_ws;
  const size_t n1 = (size_t)B_ * T_ * D_;
  float* x  = ws;
  float* qb = ws + n1;
  float* kb = ws + 2 * n1;
  float* vb = ws + 3 * n1;
  float* ob = ws + 4 * n1;
  float* yb = ws + 5 * n1;
  float* hb = qb;  // FFN hidden reuses q/k/v/o region: 4*n1 == B*T*DFF

  const int M = B_ * T_;
  dim3 blk(256);

  {
    size_t total = (size_t)B_ * T_ * D_;
    int nb = (int)((total + 255) / 256);
    embed_kernel<<<nb, blk, 0, stream>>>(runs, wickets, overs, batters, bowlers,
                                         pemb, Wf, bfv, qtok, x);
  }

  for (int l = 0; l < L_; ++l) {
    const float* Wq_l = Wq + (size_t)l * D_ * D_;
    const float* Wk_l = Wk + (size_t)l * D_ * D_;
    const float* Wv_l = Wv + (size_t)l * D_ * D_;
    const float* Wo_l = Wo + (size_t)l * D_ * D_;
    const float* W1_l = W1 + (size_t)l * D_ * DFF_;
    const float* W2_l = W2 + (size_t)l * DFF_ * D_;

    gemm_kernel<<<dim3(D_ / 64, M / 64), blk, 0, stream>>>(x, Wq_l, bq + l * D_, qb, M, D_, D_, 0);
    gemm_kernel<<<dim3(D_ / 64, M / 64), blk, 0, stream>>>(x, Wk_l, bk + l * D_, kb, M, D_, D_, 0);
    gemm_kernel<<<dim3(D_ / 64, M / 64), blk, 0, stream>>>(x, Wv_l, bv + l * D_, vb, M, D_, D_, 0);

    flash_attn_kernel<<<dim3(T_ / 64, H_, B_), blk, 0, stream>>>(
        qb, kb, vb, ob, batters, bowlers, rec_s, bow_s, bat_s, l);

    gemm_kernel<<<dim3(D_ / 64, M / 64), blk, 0, stream>>>(ob, Wo_l, bo + l * D_, yb, M, D_, D_, 0);
    add_ln_kernel<<<M, blk, 0, stream>>>(x, yb, g1 + l * D_, be1 + l * D_);

    gemm_kernel<<<dim3(DFF_ / 64, M / 64), blk, 0, stream>>>(x, W1_l, b1 + l * DFF_, hb, M, DFF_, D_, 1);
    gemm_kernel<<<dim3(D_ / 64, M / 64), blk, 0, stream>>>(hb, W2_l, b2 + l * D_, yb, M, D_, DFF_, 0);
    add_ln_kernel<<<M, blk, 0, stream>>>(x, yb, g2 + l * D_, be2 + l * D_);
  }

  final_kernel<<<dim3(B_, D_ / 256), blk, 0, stream>>>(x, Wout, bout, (float*)d_out);
}

// Round 3
// 2663.246 us; speedup vs baseline: 4.6877x; 2.9052x over previous
//
#include <hip/hip_runtime.h>
#include <math.h>

#define B_ 32
#define S_ 511
#define T_ 512
#define D_ 512
#define H_ 8
#define HD_ 64
#define L_ 4
#define P_ 501
#define PD_ 32
#define FD_ 448
#define DFF_ 2048

typedef __attribute__((ext_vector_type(8))) short bf16x8;
typedef __attribute__((ext_vector_type(4))) float f32x4;

__device__ __forceinline__ unsigned short f2bf(float f) {
  union { float f; unsigned int u; } c; c.f = f;
  unsigned int r = c.u + 0x7FFFu + ((c.u >> 16) & 1u);  // RNE
  return (unsigned short)(r >> 16);
}

// ---------------- weight transpose+convert: fp32 [K][N] -> bf16 [N][K] ----------------
__global__ __launch_bounds__(256) void wtrans_kernel(
    const float* __restrict__ in, unsigned short* __restrict__ out, int K, int N)
{
  __shared__ float t[64][65];
  const int l = blockIdx.z;
  in  += (size_t)l * K * N;
  out += (size_t)l * N * K;
  const int k0 = blockIdx.x * 64, n0 = blockIdx.y * 64;
  const int tx = threadIdx.x & 63, ty = threadIdx.x >> 6;
#pragma unroll
  for (int i = 0; i < 16; ++i) {
    int r = ty + i * 4;
    t[r][tx] = in[(size_t)(k0 + r) * N + n0 + tx];
  }
  __syncthreads();
#pragma unroll
  for (int i = 0; i < 16; ++i) {
    int r = ty + i * 4;
    out[(size_t)(n0 + r) * K + k0 + tx] = f2bf(t[tx][r]);
  }
}

// ---------------- embedding + positional encoding (dual write fp32 + bf16) ----------------
__global__ __launch_bounds__(256) void embed_kernel(
    const float* __restrict__ runs, const float* __restrict__ wickets,
    const float* __restrict__ overs, const int* __restrict__ batters,
    const int* __restrict__ bowlers, const float* __restrict__ pemb,
    const float* __restrict__ Wf, const float* __restrict__ bfv,
    const float* __restrict__ qtok, float* __restrict__ x,
    unsigned short* __restrict__ xb)
{
  size_t idx = (size_t)blockIdx.x * 256 + threadIdx.x;
  const size_t total = (size_t)B_ * T_ * D_;
  if (idx >= total) return;
  int d = (int)(idx % D_);
  int t = (int)((idx / D_) % T_);
  int b = (int)(idx / ((size_t)D_ * T_));
  float val;
  if (t < S_) {
    size_t st = (size_t)b * S_ + t;
    if (d < FD_) {
      val = runs[st] * Wf[d] + wickets[st] * Wf[FD_ + d] + overs[st] * Wf[2 * FD_ + d] + bfv[d];
    } else if (d < FD_ + PD_) {
      val = pemb[(size_t)batters[st] * PD_ + (d - FD_)];
    } else {
      val = pemb[(size_t)bowlers[st] * PD_ + (d - FD_ - PD_)];
    }
  } else {
    val = qtok[d];
  }
  float div = expf((float)(2 * (d >> 1)) * (-9.210340371976184f / (float)D_));
  float ang = (float)t * div;
  val += (d & 1) ? cosf(ang) : sinf(ang);
  x[idx] = val;
  xb[idx] = f2bf(val);
}

// ---------------- bf16 MFMA GEMM: C = A[M,K](bf16) @ Bt[N,K]^T(bf16) + bias ----------------
// 128x128 tile, BK=32, 256 threads = 4 waves (2x2), 4x4 16x16x32 frags/wave
// ACT==0: fp32 C out ; ACT==1: exact GELU then bf16 Cb out
template<int ACT>
__global__ __launch_bounds__(256) void mfma_gemm(
    const unsigned short* __restrict__ A, const unsigned short* __restrict__ Bt,
    const float* __restrict__ bias, float* __restrict__ C,
    unsigned short* __restrict__ Cb, int N, int K)
{
  __shared__ unsigned short As[128 * 32];
  __shared__ unsigned short Bs[128 * 32];
  const int tid = threadIdx.x;
  const int m0 = blockIdx.y * 128, n0 = blockIdx.x * 128;
  const int lane = tid & 63, w = tid >> 6;
  const int wr = w >> 1, wc = w & 1;
  const int lr = lane & 15, lg = lane >> 4;

  f32x4 acc[4][4] = {};

  const int sr = tid >> 2, sc8 = (tid & 3) * 8;
  const unsigned short* gA = A + (size_t)(m0 + sr) * K + sc8;
  const unsigned short* gB = Bt + (size_t)(n0 + sr) * K + sc8;
  const size_t rowK64 = (size_t)64 * K;

  for (int k0 = 0; k0 < K; k0 += 32) {
    __syncthreads();
    *(bf16x8*)&As[sr * 32 + sc8]        = *(const bf16x8*)(gA + k0);
    *(bf16x8*)&As[(sr + 64) * 32 + sc8] = *(const bf16x8*)(gA + rowK64 + k0);
    *(bf16x8*)&Bs[sr * 32 + sc8]        = *(const bf16x8*)(gB + k0);
    *(bf16x8*)&Bs[(sr + 64) * 32 + sc8] = *(const bf16x8*)(gB + rowK64 + k0);
    __syncthreads();
    bf16x8 af[4], bfr[4];
#pragma unroll
    for (int f = 0; f < 4; ++f) {
      af[f]  = *(const bf16x8*)&As[(wr * 64 + f * 16 + lr) * 32 + lg * 8];
      bfr[f] = *(const bf16x8*)&Bs[(wc * 64 + f * 16 + lr) * 32 + lg * 8];
    }
#pragma unroll
    for (int i = 0; i < 4; ++i)
#pragma unroll
      for (int j = 0; j < 4; ++j)
        acc[i][j] = __builtin_amdgcn_mfma_f32_16x16x32_bf16(af[i], bfr[j], acc[i][j], 0, 0, 0);
  }

  // epilogue: C row = (lane>>4)*4 + reg, col = lane&15  (per-frag)
  const int crow0 = m0 + wr * 64 + lg * 4;
  const int ccol0 = n0 + wc * 64 + lr;
#pragma unroll
  for (int i = 0; i < 4; ++i) {
#pragma unroll
    for (int j = 0; j < 4; ++j) {
      const int col = ccol0 + j * 16;
      const float bcol = bias[col];
#pragma unroll
      for (int r = 0; r < 4; ++r) {
        const int row = crow0 + i * 16 + r;
        float v = acc[i][j][r] + bcol;
        if (ACT == 1) {
          v = 0.5f * v * (1.0f + erff(v * 0.70710678118654752f));
          Cb[(size_t)row * N + col] = f2bf(v);
        } else {
          C[(size_t)row * N + col] = v;
        }
      }
    }
  }
}

// ---------------- tiled flash attention (fp32 compute, bf16 output) ----------------
__global__ __launch_bounds__(256) void flash_attn_kernel(
    const float* __restrict__ q, const float* __restrict__ k,
    const float* __restrict__ v, unsigned short* __restrict__ o,
    const int* __restrict__ batters, const int* __restrict__ bowlers,
    const float* __restrict__ rec_sp, const float* __restrict__ bow_sp,
    const float* __restrict__ bat_sp, int l)
{
  __shared__ float Qs[64][65];
  __shared__ float KVs[64][65];
  __shared__ float Ps[64][65];
  __shared__ float mrow[64], lrow[64], crow[64];
  __shared__ int aq_s[64], ak_s[64];

  const int qt = blockIdx.x, h = blockIdx.y, b = blockIdx.z;
  const int tid = threadIdx.x;
  const int tx = tid & 15, ty = tid >> 4;
  const int lr = tid >> 2, ldc = tid & 3;

  int mode = 0; float hs = 0.f;
  if (h == 0) { mode = 1; hs = rec_sp[l]; }
  else if (h == 1) { mode = 2; hs = bow_sp[l]; }
  else if (h == 2) { mode = 3; hs = bat_sp[l]; }
  const int* actors = (mode == 2) ? bowlers : batters;

  const int q0 = qt * 64;

  {
    const float* qp = q + ((size_t)b * T_ + q0 + lr) * D_ + h * HD_ + ldc * 16;
#pragma unroll
    for (int j = 0; j < 4; ++j) {
      float4 t4 = *(const float4*)(qp + 4 * j);
      int d0 = ldc * 16 + 4 * j;
      Qs[d0 + 0][lr] = t4.x; Qs[d0 + 1][lr] = t4.y;
      Qs[d0 + 2][lr] = t4.z; Qs[d0 + 3][lr] = t4.w;
    }
  }
  if (tid < 64) {
    int qg = q0 + tid;
    aq_s[tid] = (mode >= 2 && qg < S_) ? actors[(size_t)b * S_ + qg] : -1;
    mrow[tid] = -INFINITY;
    lrow[tid] = 0.f;
  }

  float o_acc[4][4] = {{0.f,0.f,0.f,0.f},{0.f,0.f,0.f,0.f},
                       {0.f,0.f,0.f,0.f},{0.f,0.f,0.f,0.f}};

  for (int kt = 0; kt <= qt; ++kt) {
    const int k0 = kt * 64;
    __syncthreads();
    {
      const float* kp = k + ((size_t)b * T_ + k0 + lr) * D_ + h * HD_ + ldc * 16;
#pragma unroll
      for (int j = 0; j < 4; ++j) {
        float4 t4 = *(const float4*)(kp + 4 * j);
        int d0 = ldc * 16 + 4 * j;
        KVs[d0 + 0][lr] = t4.x; KVs[d0 + 1][lr] = t4.y;
        KVs[d0 + 2][lr] = t4.z; KVs[d0 + 3][lr] = t4.w;
      }
    }
    if (tid < 64) {
      int kg = k0 + tid;
      ak_s[tid] = (mode >= 2 && kg < S_) ? actors[(size_t)b * S_ + kg] : -1;
    }
    __syncthreads();

    float acc[4][4] = {{0.f,0.f,0.f,0.f},{0.f,0.f,0.f,0.f},
                       {0.f,0.f,0.f,0.f},{0.f,0.f,0.f,0.f}};
#pragma unroll 16
    for (int d = 0; d < 64; ++d) {
      const float4 qv = *(const float4*)&Qs[d][ty * 4];
      const float4 kv = *(const float4*)&KVs[d][tx * 4];
      acc[0][0] = fmaf(qv.x, kv.x, acc[0][0]);
      acc[0][1] = fmaf(qv.x, kv.y, acc[0][1]);
      acc[0][2] = fmaf(qv.x, kv.z, acc[0][2]);
      acc[0][3] = fmaf(qv.x, kv.w, acc[0][3]);
      acc[1][0] = fmaf(qv.y, kv.x, acc[1][0]);
      acc[1][1] = fmaf(qv.y, kv.y, acc[1][1]);
      acc[1][2] = fmaf(qv.y, kv.z, acc[1][2]);
      acc[1][3] = fmaf(qv.y, kv.w, acc[1][3]);
      acc[2][0] = fmaf(qv.z, kv.x, acc[2][0]);
      acc[2][1] = fmaf(qv.z, kv.y, acc[2][1]);
      acc[2][2] = fmaf(qv.z, kv.z, acc[2][2]);
      acc[2][3] = fmaf(qv.z, kv.w, acc[2][3]);
      acc[3][0] = fmaf(qv.w, kv.x, acc[3][0]);
      acc[3][1] = fmaf(qv.w, kv.y, acc[3][1]);
      acc[3][2] = fmaf(qv.w, kv.z, acc[3][2]);
      acc[3][3] = fmaf(qv.w, kv.w, acc[3][3]);
    }
    {
      const int qg0 = q0 + ty * 4, kg0 = k0 + tx * 4;
#pragma unroll
      for (int i = 0; i < 4; ++i) {
        float4 sv;
        float* sp = (float*)&sv;
        const int qg = qg0 + i;
        const int aq = aq_s[ty * 4 + i];
#pragma unroll
        for (int j = 0; j < 4; ++j) {
          const int kg = kg0 + j;
          float s = acc[i][j] * 0.125f;
          if (mode == 1) {
            s = fmaf(hs, (float)kg * (1.0f / (float)T_), s);
          } else if (mode >= 2) {
            float eq = (qg == S_ || kg == S_) ? 1.0f
                       : ((aq == ak_s[tx * 4 + j]) ? 1.0f : 0.0f);
            s = fmaf(hs, eq, s);
          }
          if (kg > qg) s = -INFINITY;
          sp[j] = s;
        }
        *(float4*)&Ps[ty * 4 + i][tx * 4] = sv;
      }
    }
    __syncthreads();

    {
      const float* vp = v + ((size_t)b * T_ + k0 + lr) * D_ + h * HD_ + ldc * 16;
#pragma unroll
      for (int j = 0; j < 4; ++j) {
        float4 t4 = *(const float4*)(vp + 4 * j);
        int d0 = ldc * 16 + 4 * j;
        KVs[d0 + 0][lr] = t4.x; KVs[d0 + 1][lr] = t4.y;
        KVs[d0 + 2][lr] = t4.z; KVs[d0 + 3][lr] = t4.w;
      }
    }
    {
      const int qq = tid >> 2, p = tid & 3;
      float4 va[4];
#pragma unroll
      for (int u = 0; u < 4; ++u) va[u] = *(const float4*)&Ps[qq][p * 16 + 4 * u];
      float m = -INFINITY;
#pragma unroll
      for (int u = 0; u < 4; ++u) {
        m = fmaxf(m, fmaxf(fmaxf(va[u].x, va[u].y), fmaxf(va[u].z, va[u].w)));
      }
      m = fmaxf(m, __shfl_xor(m, 1));
      m = fmaxf(m, __shfl_xor(m, 2));
      const float m_old = mrow[qq];
      const float m_new = fmaxf(m_old, m);
      float sum = 0.f;
#pragma unroll
      for (int u = 0; u < 4; ++u) {
        va[u].x = expf(va[u].x - m_new);
        va[u].y = expf(va[u].y - m_new);
        va[u].z = expf(va[u].z - m_new);
        va[u].w = expf(va[u].w - m_new);
        sum += va[u].x + va[u].y + va[u].z + va[u].w;
        *(float4*)&Ps[qq][p * 16 + 4 * u] = va[u];
      }
      sum += __shfl_xor(sum, 1);
      sum += __shfl_xor(sum, 2);
      if (p == 0) {
        const float c = expf(m_old - m_new);
        crow[qq] = c;
        lrow[qq] = lrow[qq] * c + sum;
        mrow[qq] = m_new;
      }
    }
    __syncthreads();

    {
#pragma unroll
      for (int i = 0; i < 4; ++i) {
        const float c = crow[ty * 4 + i];
#pragma unroll
        for (int j = 0; j < 4; ++j) o_acc[i][j] *= c;
      }
#pragma unroll 4
      for (int k4 = 0; k4 < 64; k4 += 4) {
        float4 pv[4], vv[4];
#pragma unroll
        for (int i = 0; i < 4; ++i) pv[i] = *(const float4*)&Ps[ty * 4 + i][k4];
#pragma unroll
        for (int j = 0; j < 4; ++j) vv[j] = *(const float4*)&KVs[tx * 4 + j][k4];
#pragma unroll
        for (int i = 0; i < 4; ++i)
#pragma unroll
          for (int j = 0; j < 4; ++j)
            o_acc[i][j] = fmaf(pv[i].x, vv[j].x,
                          fmaf(pv[i].y, vv[j].y,
                          fmaf(pv[i].z, vv[j].z,
                          fmaf(pv[i].w, vv[j].w, o_acc[i][j]))));
      }
    }
  }

#pragma unroll
  for (int i = 0; i < 4; ++i) {
    const float inv = 1.0f / lrow[ty * 4 + i];
    ushort4 pk;
    pk.x = f2bf(o_acc[i][0] * inv);
    pk.y = f2bf(o_acc[i][1] * inv);
    pk.z = f2bf(o_acc[i][2] * inv);
    pk.w = f2bf(o_acc[i][3] * inv);
    *(ushort4*)&o[((size_t)b * T_ + q0 + ty * 4 + i) * D_ + h * HD_ + tx * 4] = pk;
  }
}

// ---------------- residual add + LayerNorm (dual write fp32 + bf16) ----------------
__global__ __launch_bounds__(256) void add_ln_kernel(
    float* __restrict__ x, const float* __restrict__ y,
    const float* __restrict__ g, const float* __restrict__ be,
    unsigned short* __restrict__ xb)
{
  int row = blockIdx.x;
  int tid = threadIdx.x;
  size_t base = (size_t)row * D_;
  float v0 = x[base + tid] + y[base + tid];
  float v1 = x[base + tid + 256] + y[base + tid + 256];
  float s = v0 + v1;
  float s2 = v0 * v0 + v1 * v1;
  __shared__ float redA[4], redB[4];
#pragma unroll
  for (int off = 32; off > 0; off >>= 1) {
    s  += __shfl_down(s, off);
    s2 += __shfl_down(s2, off);
  }
  if ((tid & 63) == 0) { redA[tid >> 6] = s; redB[tid >> 6] = s2; }
  __syncthreads();
  float st  = redA[0] + redA[1] + redA[2] + redA[3];
  float s2t = redB[0] + redB[1] + redB[2] + redB[3];
  float mu = st * (1.0f / (float)D_);
  float var = s2t * (1.0f / (float)D_) - mu * mu;
  float r = rsqrtf(var + 1e-5f);
  float o0 = (v0 - mu) * r * g[tid] + be[tid];
  float o1 = (v1 - mu) * r * g[tid + 256] + be[tid + 256];
  x[base + tid]        = o0;
  x[base + tid + 256]  = o1;
  xb[base + tid]       = f2bf(o0);
  xb[base + tid + 256] = f2bf(o1);
}

// ---------------- final: out[b,:] = x[b,T-1,:] @ Wout + bout ----------------
__global__ __launch_bounds__(256) void final_kernel(
    const float* __restrict__ x, const float* __restrict__ Wout,
    const float* __restrict__ bout, float* __restrict__ out)
{
  __shared__ float xs[D_];
  int b = blockIdx.x;
  int n = blockIdx.y * 256 + threadIdx.x;
  const float* xr = x + ((size_t)b * T_ + (T_ - 1)) * D_;
  xs[threadIdx.x] = xr[threadIdx.x];
  xs[threadIdx.x + 256] = xr[threadIdx.x + 256];
  __syncthreads();
  float acc = bout[n];
  for (int kk = 0; kk < D_; ++kk)
    acc = fmaf(xs[kk], Wout[(size_t)kk * D_ + n], acc);
  out[(size_t)b * D_ + n] = acc;
}

extern "C" void kernel_launch(void* const* d_in, const int* in_sizes, int n_in,
                              void* d_out, int out_size, void* d_ws, size_t ws_size,
                              hipStream_t stream)
{
  const float* runs    = (const float*)d_in[0];
  const float* wickets = (const float*)d_in[1];
  const float* overs   = (const float*)d_in[2];
  const int*   batters = (const int*)d_in[3];
  const int*   bowlers = (const int*)d_in[4];
  const float* pemb    = (const float*)d_in[5];
  const float* Wf      = (const float*)d_in[6];
  const float* bfv     = (const float*)d_in[7];
  const float* qtok    = (const float*)d_in[8];
  const float* Wq      = (const float*)d_in[9];
  const float* bq      = (const float*)d_in[10];
  const float* Wk      = (const float*)d_in[11];
  const float* bk      = (const float*)d_in[12];
  const float* Wv      = (const float*)d_in[13];
  const float* bv      = (const float*)d_in[14];
  const float* Wo      = (const float*)d_in[15];
  const float* bo      = (const float*)d_in[16];
  const float* rec_s   = (const float*)d_in[17];
  const float* bow_s   = (const float*)d_in[18];
  const float* bat_s   = (const float*)d_in[19];
  const float* W1      = (const float*)d_in[20];
  const float* b1      = (const float*)d_in[21];
  const float* W2      = (const float*)d_in[22];
  const float* b2      = (const float*)d_in[23];
  const float* g1      = (const float*)d_in[24];
  const float* be1     = (const float*)d_in[25];
  const float* g2      = (const float*)d_in[26];
  const float* be2     = (const float*)d_in[27];
  const float* Wout    = (const float*)d_in[28];
  const float* bout    = (const float*)d_in[29];

  float* ws = (float*)d_ws;
  const size_t n1 = (size_t)B_ * T_ * D_;  // 8M elements
  float* x  = ws;
  float* qb = ws + n1;
  float* kb = ws + 2 * n1;
  float* vb = ws + 3 * n1;
  float* yb = ws + 4 * n1;
  unsigned short* xb = (unsigned short*)(ws + 5 * n1);
  unsigned short* ob = xb + n1;
  unsigned short* wt = ob + n1;
  unsigned short* hb = (unsigned short*)qb;  // aliases qb+kb (dead during FFN)

  const size_t wsz = (size_t)L_ * D_ * D_;   // per family (q/k/v/o)
  unsigned short* wtq = wt;
  unsigned short* wtk = wtq + wsz;
  unsigned short* wtv = wtk + wsz;
  unsigned short* wto = wtv + wsz;
  unsigned short* wt1 = wto + wsz;                       // [DFF][D] per layer
  unsigned short* wt2 = wt1 + (size_t)L_ * D_ * DFF_;    // [D][DFF] per layer

  const int M = B_ * T_;
  dim3 blk(256);

  // weight transpose+convert (depends only on d_in)
  wtrans_kernel<<<dim3(8, 8, L_),  blk, 0, stream>>>(Wq, wtq, D_, D_);
  wtrans_kernel<<<dim3(8, 8, L_),  blk, 0, stream>>>(Wk, wtk, D_, D_);
  wtrans_kernel<<<dim3(8, 8, L_),  blk, 0, stream>>>(Wv, wtv, D_, D_);
  wtrans_kernel<<<dim3(8, 8, L_),  blk, 0, stream>>>(Wo, wto, D_, D_);
  wtrans_kernel<<<dim3(8, 32, L_), blk, 0, stream>>>(W1, wt1, D_, DFF_);
  wtrans_kernel<<<dim3(32, 8, L_), blk, 0, stream>>>(W2, wt2, DFF_, D_);

  {
    size_t total = (size_t)B_ * T_ * D_;
    int nb = (int)((total + 255) / 256);
    embed_kernel<<<nb, blk, 0, stream>>>(runs, wickets, overs, batters, bowlers,
                                         pemb, Wf, bfv, qtok, x, xb);
  }

  for (int l = 0; l < L_; ++l) {
    mfma_gemm<0><<<dim3(D_ / 128, M / 128), blk, 0, stream>>>(
        xb, wtq + (size_t)l * D_ * D_, bq + l * D_, qb, nullptr, D_, D_);
    mfma_gemm<0><<<dim3(D_ / 128, M / 128), blk, 0, stream>>>(
        xb, wtk + (size_t)l * D_ * D_, bk + l * D_, kb, nullptr, D_, D_);
    mfma_gemm<0><<<dim3(D_ / 128, M / 128), blk, 0, stream>>>(
        xb, wtv + (size_t)l * D_ * D_, bv + l * D_, vb, nullptr, D_, D_);

    flash_attn_kernel<<<dim3(T_ / 64, H_, B_), blk, 0, stream>>>(
        qb, kb, vb, ob, batters, bowlers, rec_s, bow_s, bat_s, l);

    mfma_gemm<0><<<dim3(D_ / 128, M / 128), blk, 0, stream>>>(
        ob, wto + (size_t)l * D_ * D_, bo + l * D_, yb, nullptr, D_, D_);
    add_ln_kernel<<<M, blk, 0, stream>>>(x, yb, g1 + l * D_, be1 + l * D_, xb);

    mfma_gemm<1><<<dim3(DFF_ / 128, M / 128), blk, 0, stream>>>(
        xb, wt1 + (size_t)l * D_ * DFF_, b1 + l * DFF_, nullptr, hb, DFF_, D_);
    mfma_gemm<0><<<dim3(D_ / 128, M / 128), blk, 0, stream>>>(
        hb, wt2 + (size_t)l * DFF_ * D_, b2 + l * D_, yb, nullptr, D_, DFF_);
    add_ln_kernel<<<M, blk, 0, stream>>>(x, yb, g2 + l * D_, be2 + l * D_, xb);
  }

  final_kernel<<<dim3(B_, D_ / 256), blk, 0, stream>>>(x, Wout, bout, (float*)d_out);
}

// Round 4
// 1540.436 us; speedup vs baseline: 8.1046x; 1.7289x over previous
//
#include <hip/hip_runtime.h>
#include <math.h>

#define B_ 32
#define S_ 511
#define T_ 512
#define D_ 512
#define H_ 8
#define HD_ 64
#define L_ 4
#define P_ 501
#define PD_ 32
#define FD_ 448
#define DFF_ 2048

typedef __attribute__((ext_vector_type(8))) short bf16x8;
typedef __attribute__((ext_vector_type(4))) float f32x4;

__device__ __forceinline__ unsigned short f2bf(float f) {
  union { float f; unsigned int u; } c; c.f = f;
  unsigned int r = c.u + 0x7FFFu + ((c.u >> 16) & 1u);  // RNE
  return (unsigned short)(r >> 16);
}

// ---------------- weight transpose+convert: fp32 [K][N] -> bf16 [N][K] ----------------
__global__ __launch_bounds__(256) void wtrans_kernel(
    const float* __restrict__ in, unsigned short* __restrict__ out, int K, int N)
{
  __shared__ float t[64][65];
  const int l = blockIdx.z;
  in  += (size_t)l * K * N;
  out += (size_t)l * N * K;
  const int k0 = blockIdx.x * 64, n0 = blockIdx.y * 64;
  const int tx = threadIdx.x & 63, ty = threadIdx.x >> 6;
#pragma unroll
  for (int i = 0; i < 16; ++i) {
    int r = ty + i * 4;
    t[r][tx] = in[(size_t)(k0 + r) * N + n0 + tx];
  }
  __syncthreads();
#pragma unroll
  for (int i = 0; i < 16; ++i) {
    int r = ty + i * 4;
    out[(size_t)(n0 + r) * K + k0 + tx] = f2bf(t[tx][r]);
  }
}

// ---------------- embedding + positional encoding (dual write fp32 + bf16) ----------------
__global__ __launch_bounds__(256) void embed_kernel(
    const float* __restrict__ runs, const float* __restrict__ wickets,
    const float* __restrict__ overs, const int* __restrict__ batters,
    const int* __restrict__ bowlers, const float* __restrict__ pemb,
    const float* __restrict__ Wf, const float* __restrict__ bfv,
    const float* __restrict__ qtok, float* __restrict__ x,
    unsigned short* __restrict__ xb)
{
  size_t idx = (size_t)blockIdx.x * 256 + threadIdx.x;
  const size_t total = (size_t)B_ * T_ * D_;
  if (idx >= total) return;
  int d = (int)(idx % D_);
  int t = (int)((idx / D_) % T_);
  int b = (int)(idx / ((size_t)D_ * T_));
  float val;
  if (t < S_) {
    size_t st = (size_t)b * S_ + t;
    if (d < FD_) {
      val = runs[st] * Wf[d] + wickets[st] * Wf[FD_ + d] + overs[st] * Wf[2 * FD_ + d] + bfv[d];
    } else if (d < FD_ + PD_) {
      val = pemb[(size_t)batters[st] * PD_ + (d - FD_)];
    } else {
      val = pemb[(size_t)bowlers[st] * PD_ + (d - FD_ - PD_)];
    }
  } else {
    val = qtok[d];
  }
  float div = expf((float)(2 * (d >> 1)) * (-9.210340371976184f / (float)D_));
  float ang = (float)t * div;
  val += (d & 1) ? cosf(ang) : sinf(ang);
  x[idx] = val;
  xb[idx] = f2bf(val);
}

// ---------------- bf16 MFMA GEMM ----------------
// ACT==0: fp32 C ; ACT==1: GELU -> bf16 Cb ; ACT==2: bf16 Cb
template<int ACT>
__global__ __launch_bounds__(256) void mfma_gemm(
    const unsigned short* __restrict__ A, const unsigned short* __restrict__ Bt,
    const float* __restrict__ bias, float* __restrict__ C,
    unsigned short* __restrict__ Cb, int N, int K)
{
  __shared__ unsigned short As[128 * 32];
  __shared__ unsigned short Bs[128 * 32];
  const int tid = threadIdx.x;
  const int m0 = blockIdx.y * 128, n0 = blockIdx.x * 128;
  const int lane = tid & 63, w = tid >> 6;
  const int wr = w >> 1, wc = w & 1;
  const int lr = lane & 15, lg = lane >> 4;

  f32x4 acc[4][4] = {};

  const int sr = tid >> 2, sc8 = (tid & 3) * 8;
  const unsigned short* gA = A + (size_t)(m0 + sr) * K + sc8;
  const unsigned short* gB = Bt + (size_t)(n0 + sr) * K + sc8;
  const size_t rowK64 = (size_t)64 * K;

  for (int k0 = 0; k0 < K; k0 += 32) {
    __syncthreads();
    *(bf16x8*)&As[sr * 32 + sc8]        = *(const bf16x8*)(gA + k0);
    *(bf16x8*)&As[(sr + 64) * 32 + sc8] = *(const bf16x8*)(gA + rowK64 + k0);
    *(bf16x8*)&Bs[sr * 32 + sc8]        = *(const bf16x8*)(gB + k0);
    *(bf16x8*)&Bs[(sr + 64) * 32 + sc8] = *(const bf16x8*)(gB + rowK64 + k0);
    __syncthreads();
    bf16x8 af[4], bfr[4];
#pragma unroll
    for (int f = 0; f < 4; ++f) {
      af[f]  = *(const bf16x8*)&As[(wr * 64 + f * 16 + lr) * 32 + lg * 8];
      bfr[f] = *(const bf16x8*)&Bs[(wc * 64 + f * 16 + lr) * 32 + lg * 8];
    }
#pragma unroll
    for (int i = 0; i < 4; ++i)
#pragma unroll
      for (int j = 0; j < 4; ++j)
        acc[i][j] = __builtin_amdgcn_mfma_f32_16x16x32_bf16(af[i], bfr[j], acc[i][j], 0, 0, 0);
  }

  const int crow0 = m0 + wr * 64 + lg * 4;
  const int ccol0 = n0 + wc * 64 + lr;
#pragma unroll
  for (int i = 0; i < 4; ++i) {
#pragma unroll
    for (int j = 0; j < 4; ++j) {
      const int col = ccol0 + j * 16;
      const float bcol = bias[col];
#pragma unroll
      for (int r = 0; r < 4; ++r) {
        const int row = crow0 + i * 16 + r;
        float v = acc[i][j][r] + bcol;
        if (ACT == 1) {
          v = 0.5f * v * (1.0f + erff(v * 0.70710678118654752f));
          Cb[(size_t)row * N + col] = f2bf(v);
        } else if (ACT == 2) {
          Cb[(size_t)row * N + col] = f2bf(v);
        } else {
          C[(size_t)row * N + col] = v;
        }
      }
    }
  }
}

// ---------------- V transpose: bf16 [B,T,D] -> bf16 [B,H,64,T] ----------------
__global__ __launch_bounds__(256) void vtrans_kernel(
    const unsigned short* __restrict__ vb, unsigned short* __restrict__ vt)
{
  __shared__ unsigned short tile[64 * 65];
  const int t0 = blockIdx.x * 64, h = blockIdx.y, b = blockIdx.z;
  const int tid = threadIdx.x;
  const int r = tid >> 2, ch = (tid & 3) * 16;
  const unsigned short* src = vb + ((size_t)b * T_ + t0 + r) * D_ + h * HD_ + ch;
  *(bf16x8*)&tile[r * 65 + ch]     = *(const bf16x8*)src;
  *(bf16x8*)&tile[r * 65 + ch + 8] = *(const bf16x8*)(src + 8);
  __syncthreads();
  unsigned short tmp[16];
#pragma unroll
  for (int j = 0; j < 16; ++j) tmp[j] = tile[(ch + j) * 65 + r];
  unsigned short* dst = vt + ((size_t)(b * H_ + h) * HD_ + r) * T_ + t0 + ch;
  *(bf16x8*)dst       = *(const bf16x8*)&tmp[0];
  *(bf16x8*)(dst + 8) = *(const bf16x8*)&tmp[8];
}

// ---------------- MFMA flash attention ----------------
// block = (qt, h, b), 256 threads = 4 waves, wave w owns q rows q0+w*16..+15
__global__ __launch_bounds__(256) void flash_mfma_kernel(
    const unsigned short* __restrict__ q, const unsigned short* __restrict__ k,
    const unsigned short* __restrict__ vt, unsigned short* __restrict__ o,
    const int* __restrict__ batters, const int* __restrict__ bowlers,
    const float* __restrict__ rec_sp, const float* __restrict__ bow_sp,
    const float* __restrict__ bat_sp, int l)
{
  __shared__ unsigned short QPs[64 * 70];  // Q tile, later P tile (wave-private rows)
  __shared__ unsigned short Ks[64 * 70];
  __shared__ unsigned short Vs[64 * 70];   // V^T tile: [d][k]
  __shared__ int aq_s[64], ak_s[64];

  const int qt = blockIdx.x, h = blockIdx.y, b = blockIdx.z;
  const int tid = threadIdx.x;
  const int w = tid >> 6, lane = tid & 63;
  const int c = lane & 15, g = lane >> 4;
  const int q0 = qt * 64;

  int mode = 0; float hs = 0.f;
  if (h == 0) { mode = 1; hs = rec_sp[l]; }
  else if (h == 1) { mode = 2; hs = bow_sp[l]; }
  else if (h == 2) { mode = 3; hs = bat_sp[l]; }
  const int* actors = (mode == 2) ? bowlers : batters;

  // stage Q tile [64 q][64 d]
  {
    const int r = tid >> 2, ch = (tid & 3) * 16;
    const unsigned short* src = q + ((size_t)b * T_ + q0 + r) * D_ + h * HD_ + ch;
    *(bf16x8*)&QPs[r * 70 + ch]     = *(const bf16x8*)src;
    *(bf16x8*)&QPs[r * 70 + ch + 8] = *(const bf16x8*)(src + 8);
  }
  if (tid < 64) {
    int qg_ = q0 + tid;
    aq_s[tid] = (mode >= 2 && qg_ < S_) ? actors[(size_t)b * S_ + qg_] : -1;
  }
  __syncthreads();

  // Q A-fragments (held in regs for whole kernel)
  bf16x8 af0 = *(const bf16x8*)&QPs[(w * 16 + c) * 70 + g * 8];
  bf16x8 af1 = *(const bf16x8*)&QPs[(w * 16 + c) * 70 + 32 + g * 8];

  int aq4[4];
#pragma unroll
  for (int r = 0; r < 4; ++r) aq4[r] = aq_s[w * 16 + 4 * g + r];

  float m_r[4] = {-INFINITY, -INFINITY, -INFINITY, -INFINITY};
  float l_r[4] = {0.f, 0.f, 0.f, 0.f};
  f32x4 o_acc[4] = {};  // [d-frag f][row r]

  for (int kt = 0; kt <= qt; ++kt) {
    const int k0 = kt * 64;
    __syncthreads();  // protect Ks/Vs/ak_s against previous iteration readers
    {
      const int r = tid >> 2, ch = (tid & 3) * 16;
      const unsigned short* ksrc = k + ((size_t)b * T_ + k0 + r) * D_ + h * HD_ + ch;
      *(bf16x8*)&Ks[r * 70 + ch]     = *(const bf16x8*)ksrc;
      *(bf16x8*)&Ks[r * 70 + ch + 8] = *(const bf16x8*)(ksrc + 8);
      const unsigned short* vsrc = vt + ((size_t)(b * H_ + h) * HD_ + r) * T_ + k0 + ch;
      *(bf16x8*)&Vs[r * 70 + ch]     = *(const bf16x8*)vsrc;
      *(bf16x8*)&Vs[r * 70 + ch + 8] = *(const bf16x8*)(vsrc + 8);
    }
    if (tid < 64) {
      int kg_ = k0 + tid;
      ak_s[tid] = (mode >= 2 && kg_ < S_) ? actors[(size_t)b * S_ + kg_] : -1;
    }
    __syncthreads();

    // ---- QK^T: S[16 q][64 k] per wave ----
    f32x4 s[4] = {};
#pragma unroll
    for (int f = 0; f < 4; ++f) {
      bf16x8 b0 = *(const bf16x8*)&Ks[(f * 16 + c) * 70 + g * 8];
      bf16x8 b1 = *(const bf16x8*)&Ks[(f * 16 + c) * 70 + 32 + g * 8];
      s[f] = __builtin_amdgcn_mfma_f32_16x16x32_bf16(af0, b0, s[f], 0, 0, 0);
      s[f] = __builtin_amdgcn_mfma_f32_16x16x32_bf16(af1, b1, s[f], 0, 0, 0);
    }

    // ---- scale + head bias + causal mask (C-layout: row=4g+r, col=f*16+c) ----
    int ak4[4];
#pragma unroll
    for (int f = 0; f < 4; ++f) ak4[f] = ak_s[f * 16 + c];
    float sv[4][4];
#pragma unroll
    for (int f = 0; f < 4; ++f) {
      const int kg = k0 + f * 16 + c;
#pragma unroll
      for (int r = 0; r < 4; ++r) {
        const int qg = q0 + w * 16 + 4 * g + r;
        float val = s[f][r] * 0.125f;
        if (mode == 1) {
          val = fmaf(hs, (float)kg * (1.0f / (float)T_), val);
        } else if (mode >= 2) {
          float eq = (qg == S_ || kg == S_) ? 1.0f : ((aq4[r] == ak4[f]) ? 1.0f : 0.0f);
          val = fmaf(hs, eq, val);
        }
        if (kg > qg) val = -INFINITY;
        sv[f][r] = val;
      }
    }

    // ---- online softmax (row reduce across 16 lanes of this g-group) ----
    float cr[4], rs[4];
#pragma unroll
    for (int r = 0; r < 4; ++r) {
      float pm = fmaxf(fmaxf(sv[0][r], sv[1][r]), fmaxf(sv[2][r], sv[3][r]));
      pm = fmaxf(pm, __shfl_xor(pm, 1));
      pm = fmaxf(pm, __shfl_xor(pm, 2));
      pm = fmaxf(pm, __shfl_xor(pm, 4));
      pm = fmaxf(pm, __shfl_xor(pm, 8));
      float m_new = fmaxf(m_r[r], pm);
      cr[r] = __expf(m_r[r] - m_new);
      m_r[r] = m_new;
      rs[r] = 0.f;
    }
    // P = exp(S - m), write bf16 into wave-private P region (aliases Q tile)
#pragma unroll
    for (int f = 0; f < 4; ++f) {
#pragma unroll
      for (int r = 0; r < 4; ++r) {
        float p = __expf(sv[f][r] - m_r[r]);
        rs[r] += p;
        QPs[(w * 16 + 4 * g + r) * 70 + f * 16 + c] = f2bf(p);
      }
    }
#pragma unroll
    for (int r = 0; r < 4; ++r) {
      float t = rs[r];
      t += __shfl_xor(t, 1);
      t += __shfl_xor(t, 2);
      t += __shfl_xor(t, 4);
      t += __shfl_xor(t, 8);
      l_r[r] = l_r[r] * cr[r] + t;
#pragma unroll
      for (int f = 0; f < 4; ++f) o_acc[f][r] *= cr[r];
    }

    // ---- PV: O[16 q][64 d] += P[16 q][64 k] @ V^T[d][k] ----
    bf16x8 pa0 = *(const bf16x8*)&QPs[(w * 16 + c) * 70 + g * 8];
    bf16x8 pa1 = *(const bf16x8*)&QPs[(w * 16 + c) * 70 + 32 + g * 8];
#pragma unroll
    for (int f = 0; f < 4; ++f) {
      bf16x8 v0 = *(const bf16x8*)&Vs[(f * 16 + c) * 70 + g * 8];
      bf16x8 v1 = *(const bf16x8*)&Vs[(f * 16 + c) * 70 + 32 + g * 8];
      o_acc[f] = __builtin_amdgcn_mfma_f32_16x16x32_bf16(pa0, v0, o_acc[f], 0, 0, 0);
      o_acc[f] = __builtin_amdgcn_mfma_f32_16x16x32_bf16(pa1, v1, o_acc[f], 0, 0, 0);
    }
  }

  // ---- epilogue: normalize, store bf16 ----
  float inv[4];
#pragma unroll
  for (int r = 0; r < 4; ++r) inv[r] = 1.0f / l_r[r];
#pragma unroll
  for (int f = 0; f < 4; ++f) {
#pragma unroll
    for (int r = 0; r < 4; ++r) {
      const int row = q0 + w * 16 + 4 * g + r;
      o[((size_t)b * T_ + row) * D_ + h * HD_ + f * 16 + c] = f2bf(o_acc[f][r] * inv[r]);
    }
  }
}

// ---------------- residual add + LayerNorm (dual write fp32 + bf16) ----------------
__global__ __launch_bounds__(256) void add_ln_kernel(
    float* __restrict__ x, const float* __restrict__ y,
    const float* __restrict__ g, const float* __restrict__ be,
    unsigned short* __restrict__ xb)
{
  int row = blockIdx.x;
  int tid = threadIdx.x;
  size_t base = (size_t)row * D_;
  float v0 = x[base + tid] + y[base + tid];
  float v1 = x[base + tid + 256] + y[base + tid + 256];
  float s = v0 + v1;
  float s2 = v0 * v0 + v1 * v1;
  __shared__ float redA[4], redB[4];
#pragma unroll
  for (int off = 32; off > 0; off >>= 1) {
    s  += __shfl_down(s, off);
    s2 += __shfl_down(s2, off);
  }
  if ((tid & 63) == 0) { redA[tid >> 6] = s; redB[tid >> 6] = s2; }
  __syncthreads();
  float st  = redA[0] + redA[1] + redA[2] + redA[3];
  float s2t = redB[0] + redB[1] + redB[2] + redB[3];
  float mu = st * (1.0f / (float)D_);
  float var = s2t * (1.0f / (float)D_) - mu * mu;
  float r = rsqrtf(var + 1e-5f);
  float o0 = (v0 - mu) * r * g[tid] + be[tid];
  float o1 = (v1 - mu) * r * g[tid + 256] + be[tid + 256];
  x[base + tid]        = o0;
  x[base + tid + 256]  = o1;
  xb[base + tid]       = f2bf(o0);
  xb[base + tid + 256] = f2bf(o1);
}

// ---------------- final: out[b,:] = x[b,T-1,:] @ Wout + bout ----------------
__global__ __launch_bounds__(256) void final_kernel(
    const float* __restrict__ x, const float* __restrict__ Wout,
    const float* __restrict__ bout, float* __restrict__ out)
{
  __shared__ float xs[D_];
  int b = blockIdx.x;
  int n = blockIdx.y * 256 + threadIdx.x;
  const float* xr = x + ((size_t)b * T_ + (T_ - 1)) * D_;
  xs[threadIdx.x] = xr[threadIdx.x];
  xs[threadIdx.x + 256] = xr[threadIdx.x + 256];
  __syncthreads();
  float acc = bout[n];
  for (int kk = 0; kk < D_; ++kk)
    acc = fmaf(xs[kk], Wout[(size_t)kk * D_ + n], acc);
  out[(size_t)b * D_ + n] = acc;
}

extern "C" void kernel_launch(void* const* d_in, const int* in_sizes, int n_in,
                              void* d_out, int out_size, void* d_ws, size_t ws_size,
                              hipStream_t stream)
{
  const float* runs    = (const float*)d_in[0];
  const float* wickets = (const float*)d_in[1];
  const float* overs   = (const float*)d_in[2];
  const int*   batters = (const int*)d_in[3];
  const int*   bowlers = (const int*)d_in[4];
  const float* pemb    = (const float*)d_in[5];
  const float* Wf      = (const float*)d_in[6];
  const float* bfv     = (const float*)d_in[7];
  const float* qtok    = (const float*)d_in[8];
  const float* Wq      = (const float*)d_in[9];
  const float* bq      = (const float*)d_in[10];
  const float* Wk      = (const float*)d_in[11];
  const float* bk      = (const float*)d_in[12];
  const float* Wv      = (const float*)d_in[13];
  const float* bv      = (const float*)d_in[14];
  const float* Wo      = (const float*)d_in[15];
  const float* bo      = (const float*)d_in[16];
  const float* rec_s   = (const float*)d_in[17];
  const float* bow_s   = (const float*)d_in[18];
  const float* bat_s   = (const float*)d_in[19];
  const float* W1      = (const float*)d_in[20];
  const float* b1      = (const float*)d_in[21];
  const float* W2      = (const float*)d_in[22];
  const float* b2      = (const float*)d_in[23];
  const float* g1      = (const float*)d_in[24];
  const float* be1     = (const float*)d_in[25];
  const float* g2      = (const float*)d_in[26];
  const float* be2     = (const float*)d_in[27];
  const float* Wout    = (const float*)d_in[28];
  const float* bout    = (const float*)d_in[29];

  float* ws = (float*)d_ws;
  const size_t n1 = (size_t)B_ * T_ * D_;  // 8M elements
  float* x  = ws;                                   // n1 f32
  float* yb = ws + n1;                              // n1 f32
  unsigned short* xb   = (unsigned short*)(ws + 2 * n1);
  unsigned short* qb16 = xb + n1;
  unsigned short* kb16 = qb16 + n1;
  unsigned short* vb16 = kb16 + n1;
  unsigned short* vt   = vb16 + n1;
  unsigned short* ob   = vt + n1;
  unsigned short* wt   = ob + n1;
  unsigned short* hb   = qb16;  // FFN hidden aliases qb16..vt (exactly 4*n1 shorts)

  const size_t wsz = (size_t)L_ * D_ * D_;
  unsigned short* wtq = wt;
  unsigned short* wtk = wtq + wsz;
  unsigned short* wtv = wtk + wsz;
  unsigned short* wto = wtv + wsz;
  unsigned short* wt1 = wto + wsz;
  unsigned short* wt2 = wt1 + (size_t)L_ * D_ * DFF_;

  const int M = B_ * T_;
  dim3 blk(256);

  wtrans_kernel<<<dim3(8, 8, L_),  blk, 0, stream>>>(Wq, wtq, D_, D_);
  wtrans_kernel<<<dim3(8, 8, L_),  blk, 0, stream>>>(Wk, wtk, D_, D_);
  wtrans_kernel<<<dim3(8, 8, L_),  blk, 0, stream>>>(Wv, wtv, D_, D_);
  wtrans_kernel<<<dim3(8, 8, L_),  blk, 0, stream>>>(Wo, wto, D_, D_);
  wtrans_kernel<<<dim3(8, 32, L_), blk, 0, stream>>>(W1, wt1, D_, DFF_);
  wtrans_kernel<<<dim3(32, 8, L_), blk, 0, stream>>>(W2, wt2, DFF_, D_);

  {
    size_t total = (size_t)B_ * T_ * D_;
    int nb = (int)((total + 255) / 256);
    embed_kernel<<<nb, blk, 0, stream>>>(runs, wickets, overs, batters, bowlers,
                                         pemb, Wf, bfv, qtok, x, xb);
  }

  for (int l = 0; l < L_; ++l) {
    mfma_gemm<2><<<dim3(D_ / 128, M / 128), blk, 0, stream>>>(
        xb, wtq + (size_t)l * D_ * D_, bq + l * D_, nullptr, qb16, D_, D_);
    mfma_gemm<2><<<dim3(D_ / 128, M / 128), blk, 0, stream>>>(
        xb, wtk + (size_t)l * D_ * D_, bk + l * D_, nullptr, kb16, D_, D_);
    mfma_gemm<2><<<dim3(D_ / 128, M / 128), blk, 0, stream>>>(
        xb, wtv + (size_t)l * D_ * D_, bv + l * D_, nullptr, vb16, D_, D_);

    vtrans_kernel<<<dim3(T_ / 64, H_, B_), blk, 0, stream>>>(vb16, vt);

    flash_mfma_kernel<<<dim3(T_ / 64, H_, B_), blk, 0, stream>>>(
        qb16, kb16, vt, ob, batters, bowlers, rec_s, bow_s, bat_s, l);

    mfma_gemm<0><<<dim3(D_ / 128, M / 128), blk, 0, stream>>>(
        ob, wto + (size_t)l * D_ * D_, bo + l * D_, yb, nullptr, D_, D_);
    add_ln_kernel<<<M, blk, 0, stream>>>(x, yb, g1 + l * D_, be1 + l * D_, xb);

    mfma_gemm<1><<<dim3(DFF_ / 128, M / 128), blk, 0, stream>>>(
        xb, wt1 + (size_t)l * D_ * DFF_, b1 + l * DFF_, nullptr, hb, DFF_, D_);
    mfma_gemm<0><<<dim3(D_ / 128, M / 128), blk, 0, stream>>>(
        hb, wt2 + (size_t)l * DFF_ * D_, b2 + l * D_, yb, nullptr, D_, DFF_);
    add_ln_kernel<<<M, blk, 0, stream>>>(x, yb, g2 + l * D_, be2 + l * D_, xb);
  }

  final_kernel<<<dim3(B_, D_ / 256), blk, 0, stream>>>(x, Wout, bout, (float*)d_out);
}